// Round 11
// baseline (383.717 us; speedup 1.0000x reference)
//
#include <hip/hip_runtime.h>

// DonutSwinAttention: hs[2048,49,384] fp32 -> out[2048,49,384] fp32
// Pipeline: prep(W^T->bf16, comb=rpb+mask) ; QKV GEMM (fp32-A fused convert) ;
//           MFMA attention v3 (R8) ; O-proj GEMM (R4)
// R11: kill prep_x (37us, 231MB pure traffic): qkv stages fp32 X via global_load_lds
//      (32KB A-tile, 48KB LDS total), converts to bf16 in-register at fragment read
//      (2x ds_read_b128 + 4x v_cvt_pk_bf16_f32). Same R4 block count & barrier structure.
//      attn reverted to R8 v3 (R10 per-si restructure was neutral-negative).

typedef unsigned short u16;
typedef unsigned int   u32;
typedef short bf16x8 __attribute__((ext_vector_type(8)));   // MFMA A/B operand (8 bf16)
typedef float f32x4  __attribute__((ext_vector_type(4)));   // MFMA C/D
typedef u16   u16x8  __attribute__((ext_vector_type(8)));
typedef u16   u16x4  __attribute__((ext_vector_type(4)));

#define NWIN   2048
#define SEQ    49
#define DIM    384
#define NH     12
#define HD     32
#define MTOT   (NWIN*SEQ)      // 100352 = 784*128
#define WELEM  (DIM*DIM)       // 147456

__device__ __forceinline__ u16 f2b(float f) {               // fp32 -> bf16 RTN-even
    union { float f; unsigned u; } c; c.f = f;
    unsigned u = c.u;
    u += 0x7FFFu + ((u >> 16) & 1u);
    return (u16)(u >> 16);
}

// ---------------- prep kernels ----------------
__global__ __launch_bounds__(256) void prep_w(const float* __restrict__ qW, const float* __restrict__ kW,
                                              const float* __restrict__ vW, const float* __restrict__ oW,
                                              u16* __restrict__ Wt) {
    int t = blockIdx.x * 256 + threadIdx.x;      // 589,824 exact
    int m = t / WELEM; int rem = t - m * WELEM;
    int k = rem / DIM; int n = rem - k * DIM;
    const float* src = (m==0) ? qW : (m==1) ? kW : (m==2) ? vW : oW;
    Wt[m*WELEM + n*DIM + k] = f2b(src[rem]);     // Wt[m][n][k] = W[k][n]
}

// comb[wm][h][s64][t64] = rpb[h][s][t] + mask[wm][s][t], pads = -1e30 (p==0 exactly).
__global__ __launch_bounds__(256) void prep_comb(const float* __restrict__ bt, const int* __restrict__ ridx,
                                                 const float* __restrict__ mask, float* __restrict__ comb) {
    int idx = blockIdx.x * 256 + threadIdx.x;    // 3,145,728 exact (12288 blocks)
    int t = idx & 63, s = (idx >> 6) & 63;
    int hw = idx >> 12;                          // 0..767
    int h = hw % NH, wm = hw / NH;
    float v = -1e30f;
    if (s < SEQ && t < SEQ) {
        int st = s * SEQ + t;
        v = bt[ridx[st] * NH + h] + mask[wm * (SEQ*SEQ) + st];
    }
    comb[idx] = v;
}

// ---------------- async DMA helper ----------------
__device__ __forceinline__ void gload_lds16(const void* g, void* l) {
    __builtin_amdgcn_global_load_lds((const __attribute__((address_space(1))) void*)g,
                                     (__attribute__((address_space(3))) void*)l, 16, 0, 0);
}

// ---------------- bf16 stage (B operands, oproj A): LDS[row][x] = G[row][x^((row&7)<<3)] ----------------
__device__ __forceinline__ void stage_tile_async(const u16* __restrict__ g0, u16* lds, int wv, int lane) {
    const int r8   = lane >> 3;                         // row & 7 within every 8-row stripe
    const int scol = ((lane & 7) * 8) ^ (r8 << 3);      // pre-swizzled source col (elements)
    const u16* src = g0 + (wv * 8 + r8) * DIM + scol;
    u16*       dst = lds + wv * 512 + lane * 8;         // linear: wave base + lane*16B
    #pragma unroll
    for (int i = 0; i < 4; i++)                         // rows i*32 + wv*8 + r8
        gload_lds16(src + i * 32 * DIM, dst + i * 2048);
}

// ---------------- qkv mainloop: fp32 A + bf16 B, 128x128 tile, BK=64, 4 waves (2x2) ----------------
// A LDS (fp32, 256B rows, 16 chunks of 16B): LDS[row][c16] = G[row][c16 ^ (row&7)].
__device__ __forceinline__ void gemm_tile_xf32(const float* __restrict__ Abase, const u16* __restrict__ Bbase,
                                               f32x4 (&acc)[4][4]) {
    __shared__ __align__(16) float Af[128 * 64];        // 32KB
    __shared__ __align__(16) u16   Bs[128 * 64];        // 16KB
    const int tid = threadIdx.x, wave = tid >> 6, lane = tid & 63;
    const int wm = wave >> 1, wn = wave & 1;
    const int swzl  = (lane & 7) << 3;                  // B read swizzle (u16 units)
    const int aswz  = lane & 7;                         // A read swizzle (c16 units), row&7 == lane&7
    const int c16s  = lane & 15;                        // A stage: this lane's chunk16 slot
    const int rofs  = lane >> 4;                        // A stage: row within 4-row DMA group

    for (int kt = 0; kt < 6; kt++) {
        __syncthreads();                                // prev ds_reads done before DMA overwrite
        // stage A: 8 DMAs/wave, each covers 4 rows x 16 chunk16 (1KB)
        #pragma unroll
        for (int jA = 0; jA < 8; jA++) {
            const int row0 = (jA >> 1) * 32 + wave * 8 + (jA & 1) * 4;     // tile row of lane group 0
            const int r    = row0 + rofs;
            const float* src = Abase + r * DIM + kt * 64 + ((c16s ^ (r & 7)) << 2);
            float*       dst = Af + row0 * 64 + lane * 4;                  // linear 4 rows
            gload_lds16(src, dst);
        }
        stage_tile_async(Bbase + kt * 64, Bs, wave, lane);
        __syncthreads();                                // drains vmcnt(0): DMA writes visible
        #pragma unroll
        for (int kk = 0; kk < 2; kk++) {
            const int c16l = kk * 8 + ((lane >> 4) << 1);      // logical chunk16 of frag start
            const int co   = (kk * 32 + (lane >> 4) * 8) ^ swzl;
            bf16x8 a[4], b[4];
            #pragma unroll
            for (int mi = 0; mi < 4; mi++) {
                const int r = wm * 64 + mi * 16 + (lane & 15);
                const float4 fa = *(const float4*)&Af[r * 64 + ((c16l     ^ aswz) << 2)];
                const float4 fb = *(const float4*)&Af[r * 64 + (((c16l+1) ^ aswz) << 2)];
                union { u32 u[4]; bf16x8 v; } cv;
                asm("v_cvt_pk_bf16_f32 %0, %1, %2" : "=v"(cv.u[0]) : "v"(fa.x), "v"(fa.y));
                asm("v_cvt_pk_bf16_f32 %0, %1, %2" : "=v"(cv.u[1]) : "v"(fa.z), "v"(fa.w));
                asm("v_cvt_pk_bf16_f32 %0, %1, %2" : "=v"(cv.u[2]) : "v"(fb.x), "v"(fb.y));
                asm("v_cvt_pk_bf16_f32 %0, %1, %2" : "=v"(cv.u[3]) : "v"(fb.z), "v"(fb.w));
                a[mi] = cv.v;
            }
            #pragma unroll
            for (int ni = 0; ni < 4; ni++)
                b[ni] = *(const bf16x8*)&Bs[(wn * 64 + ni * 16 + (lane & 15)) * 64 + co];
            #pragma unroll
            for (int mi = 0; mi < 4; mi++)
                #pragma unroll
                for (int ni = 0; ni < 4; ni++)
                    acc[mi][ni] = __builtin_amdgcn_mfma_f32_16x16x32_bf16(a[mi], b[ni], acc[mi][ni], 0, 0, 0);
        }
    }
}

// ---------------- oproj mainloop: R4 bf16 structure ----------------
__device__ __forceinline__ void gemm_tile(const u16* __restrict__ Abase, const u16* __restrict__ Bbase,
                                          f32x4 (&acc)[4][4]) {
    __shared__ __align__(16) u16 As[128 * 64];
    __shared__ __align__(16) u16 Bs[128 * 64];
    const int tid = threadIdx.x, wave = tid >> 6, lane = tid & 63;
    const int wm = wave >> 1, wn = wave & 1;
    const int swzl = (lane & 7) << 3;            // fragment rows have row&7 == lane&7
    for (int kt = 0; kt < 6; kt++) {
        __syncthreads();
        stage_tile_async(Abase + kt * 64, As, wave, lane);
        stage_tile_async(Bbase + kt * 64, Bs, wave, lane);
        __syncthreads();
        #pragma unroll
        for (int kk = 0; kk < 2; kk++) {
            const int co = (kk * 32 + (lane >> 4) * 8) ^ swzl;
            bf16x8 a[4], b[4];
            #pragma unroll
            for (int mi = 0; mi < 4; mi++)
                a[mi] = *(const bf16x8*)&As[(wm * 64 + mi * 16 + (lane & 15)) * 64 + co];
            #pragma unroll
            for (int ni = 0; ni < 4; ni++)
                b[ni] = *(const bf16x8*)&Bs[(wn * 64 + ni * 16 + (lane & 15)) * 64 + co];
            #pragma unroll
            for (int mi = 0; mi < 4; mi++)
                #pragma unroll
                for (int ni = 0; ni < 4; ni++)
                    acc[mi][ni] = __builtin_amdgcn_mfma_f32_16x16x32_bf16(a[mi], b[ni], acc[mi][ni], 0, 0, 0);
        }
    }
}

// ---------------- QKV projection (reads fp32 X) ----------------
__global__ __launch_bounds__(256) void qkv_gemm(const float* __restrict__ X, const u16* __restrict__ Wt,
                                                const float* __restrict__ qb, const float* __restrict__ kb,
                                                const float* __restrict__ vb,
                                                u16* __restrict__ Qo, u16* __restrict__ Ko, u16* __restrict__ Vo) {
    const int bid = blockIdx.x;                   // 0..7055 (= 784*9, %8 == 0)
    const int swz = (bid & 7) * 882 + (bid >> 3);
    const int mTile = swz / 9, p = swz - mTile * 9;
    const int mBase = mTile * 128;
    const int proj = p / 3, nBase = (p - proj * 3) * 128;
    f32x4 acc[4][4];
    #pragma unroll
    for (int mi = 0; mi < 4; mi++)
        #pragma unroll
        for (int ni = 0; ni < 4; ni++) { f32x4 z = {0.f,0.f,0.f,0.f}; acc[mi][ni] = z; }

    gemm_tile_xf32(X + (size_t)mBase * DIM, Wt + proj * WELEM + nBase * DIM, acc);

    const float* bias = (proj==0) ? qb : (proj==1) ? kb : vb;
    u16* Out          = (proj==0) ? Qo : (proj==1) ? Ko : Vo;
    const float scale = (proj==0) ? 0.17677669529663687f : 1.0f;   // fold 1/sqrt(32) into Q
    const int tid = threadIdx.x, wave = tid >> 6, lane = tid & 63;
    const int wm = wave >> 1, wn = wave & 1;

    float bias4[4]; int hh[4], dd[4];
    #pragma unroll
    for (int ni = 0; ni < 4; ni++) {
        int nin = nBase + wn * 64 + ni * 16 + (lane & 15);
        bias4[ni] = bias[nin]; hh[ni] = nin >> 5; dd[ni] = nin & 31;
    }
    #pragma unroll
    for (int mi = 0; mi < 4; mi++) {
        #pragma unroll
        for (int j = 0; j < 4; j++) {
            int gm = mBase + wm * 64 + mi * 16 + ((lane >> 4) << 2) + j;
            int bw = gm / SEQ, s = gm - bw * SEQ;
            int rowbase = (bw * (NH*SEQ) + s) * HD;
            #pragma unroll
            for (int ni = 0; ni < 4; ni++) {
                float val = (acc[mi][ni][j] + bias4[ni]) * scale;
                Out[rowbase + hh[ni] * (SEQ*HD) + dd[ni]] = f2b(val);
            }
        }
    }
}

// ---------------- MFMA attention v3 (R8, known-best) ----------------
// Block = (wm, h, half): comb panel staged once in LDS, reused by 16 windows (4 waves x 4 iters).
__global__ __launch_bounds__(256) void attn_mfma(const u16* __restrict__ Qb, const u16* __restrict__ Kb,
                                                 const u16* __restrict__ Vb, const float* __restrict__ comb,
                                                 u16* __restrict__ Ctx) {
    const int tid = threadIdx.x, wv = tid >> 6, lane = tid & 63;
    const int r16 = lane & 15, g = lane >> 4;
    const int bid = blockIdx.x;                   // 0..1535
    const int half = bid & 1, wh = bid >> 1;      // wh = wm*12 + h
    const int wm = wh / NH, h = wh - wm * NH;

    __shared__ float clds[64][68];                // +4 pad: compute reads 2-way-conflict (free)
    {
        const float4* cp = (const float4*)(comb + (size_t)wh * 4096);
        #pragma unroll
        for (int i0 = 0; i0 < 4; i0++) {
            int i = i0 * 256 + tid;               // 1024 float4s, coalesced
            float4 v = cp[i];
            *(float4*)&clds[i >> 4][(i & 15) * 4] = v;
        }
    }
    __syncthreads();

    for (int it = 0; it < 4; it++) {
        const int j = half * 16 + it * 4 + wv;    // 0..31
        const int w = j * 64 + wm;
        const int idx = w * NH + h;
        const u16* Qp = Qb + idx * (SEQ*HD);
        const u16* Kp = Kb + idx * (SEQ*HD);
        const u16* Vp = Vb + idx * (SEQ*HD);
        // NOTE: fragment loads for rows >= 49 read past the panel into the adjacent
        // region — finite deterministic data, masked to p=0 by comb=-1e30.

        bf16x8 kf[4], qf[4];
        #pragma unroll
        for (int ti = 0; ti < 4; ti++) kf[ti] = *(const bf16x8*)&Kp[(ti*16 + r16)*HD + g*8];
        #pragma unroll
        for (int si = 0; si < 4; si++) qf[si] = *(const bf16x8*)&Qp[(si*16 + r16)*HD + g*8];

        f32x4 st[4][4];                           // S^T tiles [ti][si]
        __builtin_amdgcn_s_setprio(1);
        #pragma unroll
        for (int ti = 0; ti < 4; ti++)
            #pragma unroll
            for (int si = 0; si < 4; si++) {
                f32x4 z = {0.f,0.f,0.f,0.f};
                st[ti][si] = __builtin_amdgcn_mfma_f32_16x16x32_bf16(kf[ti], qf[si], z, 0, 0, 0);
            }
        __builtin_amdgcn_s_setprio(0);

        // add comb: S^T[t][s] += comb[s][t]
        #pragma unroll
        for (int ti = 0; ti < 4; ti++)
            #pragma unroll
            for (int si = 0; si < 4; si++) {
                const float4 c = *(const float4*)&clds[si*16 + r16][ti*16 + g*4];
                st[ti][si][0] += c.x; st[ti][si][1] += c.y; st[ti][si][2] += c.z; st[ti][si][3] += c.w;
            }

        // softmax over t (per row s): regs (ti,r) + lane bits 4,5
        #pragma unroll
        for (int si = 0; si < 4; si++) {
            float m = st[0][si][0];
            #pragma unroll
            for (int ti = 0; ti < 4; ti++)
                #pragma unroll
                for (int r = 0; r < 4; r++) m = fmaxf(m, st[ti][si][r]);
            m = fmaxf(m, __shfl_xor(m, 16));
            m = fmaxf(m, __shfl_xor(m, 32));
            float sum = 0.f;
            #pragma unroll
            for (int ti = 0; ti < 4; ti++)
                #pragma unroll
                for (int r = 0; r < 4; r++) {
                    float p = __expf(st[ti][si][r] - m);
                    st[ti][si][r] = p; sum += p;
                }
            sum += __shfl_xor(sum, 16);
            sum += __shfl_xor(sum, 32);
            float rs = 1.0f / sum;
            #pragma unroll
            for (int ti = 0; ti < 4; ti++)
                #pragma unroll
                for (int r = 0; r < 4; r++) st[ti][si][r] *= rs;
        }

        // pack P^T pairs to bf16
        u32 pk[4][4][2];
        #pragma unroll
        for (int ti = 0; ti < 4; ti++)
            #pragma unroll
            for (int si = 0; si < 4; si++)
                #pragma unroll
                for (int q = 0; q < 2; q++) {
                    u32 r;
                    asm("v_cvt_pk_bf16_f32 %0, %1, %2" : "=v"(r) : "v"(st[ti][si][2*q]), "v"(st[ti][si][2*q+1]));
                    pk[ti][si][q] = r;
                }

        // PV A-frags via lane-group shuffles
        bf16x8 pa[2][4];                          // [kc][si]
        const int base_src = r16 + ((g & 1) << 5);
        #pragma unroll
        for (int kc = 0; kc < 2; kc++)
            #pragma unroll
            for (int si = 0; si < 4; si++) {
                union { u32 u[4]; bf16x8 v; } cv;
                #pragma unroll
                for (int jj = 0; jj < 4; jj++) {
                    int srcl = base_src + ((jj >> 1) << 4);
                    u32 x0 = (u32)__shfl((int)pk[kc*2 + 0][si][jj & 1], srcl);
                    u32 x1 = (u32)__shfl((int)pk[kc*2 + 1][si][jj & 1], srcl);
                    cv.u[jj] = (lane >= 32) ? x1 : x0;
                }
                pa[kc][si] = cv.v;
            }

        // V B-frags: B[d][t] = V[t][d]; scalar gather (16-lane groups hit 32B segments, L2-hot)
        bf16x8 vf[2][2];                          // [kc][nt]
        #pragma unroll
        for (int kc = 0; kc < 2; kc++)
            #pragma unroll
            for (int nt = 0; nt < 2; nt++) {
                bf16x8 v;
                #pragma unroll
                for (int i = 0; i < 8; i++)
                    v[i] = (short)Vp[(kc*32 + g*8 + i)*HD + nt*16 + r16];
                vf[kc][nt] = v;
            }

        f32x4 ct[4][2];                           // ctx tiles [si][nt]
        __builtin_amdgcn_s_setprio(1);
        #pragma unroll
        for (int si = 0; si < 4; si++)
            #pragma unroll
            for (int nt = 0; nt < 2; nt++) {
                f32x4 z = {0.f,0.f,0.f,0.f};
                z = __builtin_amdgcn_mfma_f32_16x16x32_bf16(pa[0][si], vf[0][nt], z, 0, 0, 0);
                ct[si][nt] = __builtin_amdgcn_mfma_f32_16x16x32_bf16(pa[1][si], vf[1][nt], z, 0, 0, 0);
            }
        __builtin_amdgcn_s_setprio(0);

        // store ctx[s][d] -> Ctx[w*49+s][h*32+d]
        #pragma unroll
        for (int si = 0; si < 4; si++)
            #pragma unroll
            for (int r = 0; r < 4; r++) {
                int s = si*16 + g*4 + r;
                if (s < SEQ) {
                    #pragma unroll
                    for (int nt = 0; nt < 2; nt++)
                        Ctx[(w*SEQ + s)*DIM + h*HD + nt*16 + r16] = f2b(ct[si][nt][r]);
                }
            }
    }
}

// ---------------- output projection ----------------
__global__ __launch_bounds__(256) void oproj_gemm(const u16* __restrict__ Cb, const u16* __restrict__ Wo,
                                                  const float* __restrict__ ob, float* __restrict__ out) {
    const int bid = blockIdx.x;                   // 0..2351 (= 784*3, %8 == 0)
    const int swz = (bid & 7) * 294 + (bid >> 3);
    const int mTile = swz / 3, nTile = swz - mTile * 3;
    const int mBase = mTile * 128, nBase = nTile * 128;
    f32x4 acc[4][4];
    #pragma unroll
    for (int mi = 0; mi < 4; mi++)
        #pragma unroll
        for (int ni = 0; ni < 4; ni++) { f32x4 z = {0.f,0.f,0.f,0.f}; acc[mi][ni] = z; }

    gemm_tile(Cb + mBase * DIM, Wo + nBase * DIM, acc);

    const int tid = threadIdx.x, wave = tid >> 6, lane = tid & 63;
    const int wm = wave >> 1, wn = wave & 1;
    float ob4[4]; int gn4[4];
    #pragma unroll
    for (int ni = 0; ni < 4; ni++) {
        gn4[ni] = nBase + wn * 64 + ni * 16 + (lane & 15);
        ob4[ni] = ob[gn4[ni]];
    }
    #pragma unroll
    for (int mi = 0; mi < 4; mi++) {
        #pragma unroll
        for (int j = 0; j < 4; j++) {
            int gm = mBase + wm * 64 + mi * 16 + ((lane >> 4) << 2) + j;
            #pragma unroll
            for (int ni = 0; ni < 4; ni++)
                out[gm * DIM + gn4[ni]] = acc[mi][ni][j] + ob4[ni];
        }
    }
}

// ---------------- launch ----------------
extern "C" void kernel_launch(void* const* d_in, const int* in_sizes, int n_in,
                              void* d_out, int out_size, void* d_ws, size_t ws_size,
                              hipStream_t stream) {
    const float* hs   = (const float*)d_in[0];
    const float* mask = (const float*)d_in[1];
    const float* qW   = (const float*)d_in[2];
    const float* qb   = (const float*)d_in[3];
    const float* kW   = (const float*)d_in[4];
    const float* kb   = (const float*)d_in[5];
    const float* vW   = (const float*)d_in[6];
    const float* vb   = (const float*)d_in[7];
    const float* oW   = (const float*)d_in[8];
    const float* ob   = (const float*)d_in[9];
    const float* bt   = (const float*)d_in[10];
    const int*   ridx = (const int*)d_in[11];
    float* out = (float*)d_out;

    char* ws = (char*)d_ws;
    // layout (bytes): Ctx 77,070,336 | Q | K | V | Wt | comb(12.6MB)
    u16* Ctx  = (u16*)(ws);
    u16* Qb   = (u16*)(ws + 77070336);
    u16* Kb   = (u16*)(ws + 154140672);
    u16* Vb   = (u16*)(ws + 231211008);
    u16* Wt   = (u16*)(ws + 308281344);
    float* comb = (float*)(ws + 309460992);       // 64*12*64*64 fp32 = 12,582,912 B

    prep_w   <<<2304, 256, 0, stream>>>(qW, kW, vW, oW, Wt);
    prep_comb<<<12288, 256, 0, stream>>>(bt, ridx, mask, comb);
    qkv_gemm <<<7056, 256, 0, stream>>>(hs, Wt, qb, kb, vb, Qb, Kb, Vb);
    attn_mfma<<<1536, 256, 0, stream>>>(Qb, Kb, Vb, comb, Ctx);
    oproj_gemm<<<2352, 256, 0, stream>>>(Ctx, Wt + 3 * WELEM, ob, out);
}

// Round 12
// 339.837 us; speedup vs baseline: 1.1291x; 1.1291x over previous
//
#include <hip/hip_runtime.h>

// DonutSwinAttention: hs[2048,49,384] fp32 -> out[2048,49,384] fp32
// Pipeline: prep_all(X->bf16 | W^T->bf16 | comb=log2e*(rpb+mask)) ; QKV GEMM (R4) ;
//           MFMA attention v3 (R8, exp2-domain softmax) ; O-proj GEMM (R4)
// R12: revert R11 (fp32-A fuse regressed: wrong swizzle -> 8-way LDS conflicts).
//      Safe stack: merged prep dispatch + log2e folding (v_exp_f32 direct).

typedef unsigned short u16;
typedef unsigned int   u32;
typedef short bf16x8 __attribute__((ext_vector_type(8)));   // MFMA A/B operand (8 bf16)
typedef float f32x4  __attribute__((ext_vector_type(4)));   // MFMA C/D
typedef u16   u16x8  __attribute__((ext_vector_type(8)));
typedef u16   u16x4  __attribute__((ext_vector_type(4)));

#define NWIN   2048
#define SEQ    49
#define DIM    384
#define NH     12
#define HD     32
#define MTOT   (NWIN*SEQ)      // 100352 = 784*128
#define WELEM  (DIM*DIM)       // 147456
#define LOG2E  1.4426950408889634f

__device__ __forceinline__ u16 f2b(float f) {               // fp32 -> bf16 RTN-even
    union { float f; unsigned u; } c; c.f = f;
    unsigned u = c.u;
    u += 0x7FFFu + ((u >> 16) & 1u);
    return (u16)(u >> 16);
}

// ---------------- merged prep: [0,37632) X->bf16 | [37632,39936) W^T | [39936,52224) comb ----------------
__global__ __launch_bounds__(256) void prep_all(const float* __restrict__ X, u16* __restrict__ Xb,
                                                const float* __restrict__ qW, const float* __restrict__ kW,
                                                const float* __restrict__ vW, const float* __restrict__ oW,
                                                u16* __restrict__ Wt,
                                                const float* __restrict__ bt, const int* __restrict__ ridx,
                                                const float* __restrict__ mask, float* __restrict__ comb) {
    const int bid = blockIdx.x;
    if (bid < 37632) {                            // X -> bf16 (9,633,792 float4s exact)
        int i = bid * 256 + threadIdx.x;
        float4 v = ((const float4*)X)[i];
        u16x4 o; o[0]=f2b(v.x); o[1]=f2b(v.y); o[2]=f2b(v.z); o[3]=f2b(v.w);
        ((u16x4*)Xb)[i] = o;
    } else if (bid < 39936) {                     // W^T -> bf16 (589,824 exact)
        int t = (bid - 37632) * 256 + threadIdx.x;
        int m = t / WELEM; int rem = t - m * WELEM;
        int k = rem / DIM; int n = rem - k * DIM;
        const float* src = (m==0) ? qW : (m==1) ? kW : (m==2) ? vW : oW;
        Wt[m*WELEM + n*DIM + k] = f2b(src[rem]); // Wt[m][n][k] = W[k][n]
    } else {                                      // comb[wm][h][s64][t64], exp2-domain (x log2e)
        int idx = (bid - 39936) * 256 + threadIdx.x;   // 3,145,728 exact
        int t = idx & 63, s = (idx >> 6) & 63;
        int hw = idx >> 12;                       // 0..767
        int h = hw % NH, wm = hw / NH;
        float v = -1e30f;                         // pad: exp2 -> exact 0
        if (s < SEQ && t < SEQ) {
            int st = s * SEQ + t;
            v = (bt[ridx[st] * NH + h] + mask[wm * (SEQ*SEQ) + st]) * LOG2E;
        }
        comb[idx] = v;
    }
}

// ---------------- shared GEMM mainloop: 128x128 tile, K=384, BK=64, 4 waves (2x2) ----------------
// R4 known-best structure. LDS[row][x] = G[row][x ^ ((row&7)<<3)] (element units).
__device__ __forceinline__ void gload_lds16(const void* g, void* l) {
    __builtin_amdgcn_global_load_lds((const __attribute__((address_space(1))) void*)g,
                                     (__attribute__((address_space(3))) void*)l, 16, 0, 0);
}

__device__ __forceinline__ void stage_tile_async(const u16* __restrict__ g0, u16* lds, int wv, int lane) {
    const int r8   = lane >> 3;                         // row & 7 within every 8-row stripe
    const int scol = ((lane & 7) * 8) ^ (r8 << 3);      // pre-swizzled source col (elements)
    const u16* src = g0 + (wv * 8 + r8) * DIM + scol;
    u16*       dst = lds + wv * 512 + lane * 8;         // linear: wave base + lane*16B
    #pragma unroll
    for (int i = 0; i < 4; i++)                         // rows i*32 + wv*8 + r8
        gload_lds16(src + i * 32 * DIM, dst + i * 2048);
}

__device__ __forceinline__ void gemm_tile(const u16* __restrict__ Abase, const u16* __restrict__ Bbase,
                                          f32x4 (&acc)[4][4]) {
    __shared__ __align__(16) u16 As[128 * 64];
    __shared__ __align__(16) u16 Bs[128 * 64];
    const int tid = threadIdx.x, wave = tid >> 6, lane = tid & 63;
    const int wm = wave >> 1, wn = wave & 1;
    const int swzl = (lane & 7) << 3;            // fragment rows have row&7 == lane&7
    for (int kt = 0; kt < 6; kt++) {
        __syncthreads();                          // prev ds_reads done before DMA overwrite
        stage_tile_async(Abase + kt * 64, As, wave, lane);
        stage_tile_async(Bbase + kt * 64, Bs, wave, lane);
        __syncthreads();                          // drains vmcnt(0): DMA writes visible
        #pragma unroll
        for (int kk = 0; kk < 2; kk++) {
            const int co = (kk * 32 + (lane >> 4) * 8) ^ swzl;
            bf16x8 a[4], b[4];
            #pragma unroll
            for (int mi = 0; mi < 4; mi++)
                a[mi] = *(const bf16x8*)&As[(wm * 64 + mi * 16 + (lane & 15)) * 64 + co];
            #pragma unroll
            for (int ni = 0; ni < 4; ni++)
                b[ni] = *(const bf16x8*)&Bs[(wn * 64 + ni * 16 + (lane & 15)) * 64 + co];
            #pragma unroll
            for (int mi = 0; mi < 4; mi++)
                #pragma unroll
                for (int ni = 0; ni < 4; ni++)
                    acc[mi][ni] = __builtin_amdgcn_mfma_f32_16x16x32_bf16(a[mi], b[ni], acc[mi][ni], 0, 0, 0);
        }
    }
}

// ---------------- QKV projection ----------------
__global__ __launch_bounds__(256) void qkv_gemm(const u16* __restrict__ Xb, const u16* __restrict__ Wt,
                                                const float* __restrict__ qb, const float* __restrict__ kb,
                                                const float* __restrict__ vb,
                                                u16* __restrict__ Qo, u16* __restrict__ Ko, u16* __restrict__ Vo) {
    const int bid = blockIdx.x;                   // 0..7055 (= 784*9, %8 == 0)
    const int swz = (bid & 7) * 882 + (bid >> 3);
    const int mTile = swz / 9, p = swz - mTile * 9;
    const int mBase = mTile * 128;
    const int proj = p / 3, nBase = (p - proj * 3) * 128;
    f32x4 acc[4][4];
    #pragma unroll
    for (int mi = 0; mi < 4; mi++)
        #pragma unroll
        for (int ni = 0; ni < 4; ni++) { f32x4 z = {0.f,0.f,0.f,0.f}; acc[mi][ni] = z; }

    gemm_tile(Xb + mBase * DIM, Wt + proj * WELEM + nBase * DIM, acc);

    const float* bias = (proj==0) ? qb : (proj==1) ? kb : vb;
    u16* Out          = (proj==0) ? Qo : (proj==1) ? Ko : Vo;
    // Q scale folds 1/sqrt(32) AND log2e (exp2-domain softmax)
    const float scale = (proj==0) ? (0.17677669529663687f * LOG2E) : 1.0f;
    const int tid = threadIdx.x, wave = tid >> 6, lane = tid & 63;
    const int wm = wave >> 1, wn = wave & 1;

    float bias4[4]; int hh[4], dd[4];
    #pragma unroll
    for (int ni = 0; ni < 4; ni++) {
        int nin = nBase + wn * 64 + ni * 16 + (lane & 15);
        bias4[ni] = bias[nin]; hh[ni] = nin >> 5; dd[ni] = nin & 31;
    }
    #pragma unroll
    for (int mi = 0; mi < 4; mi++) {
        #pragma unroll
        for (int j = 0; j < 4; j++) {
            int gm = mBase + wm * 64 + mi * 16 + ((lane >> 4) << 2) + j;
            int bw = gm / SEQ, s = gm - bw * SEQ;
            int rowbase = (bw * (NH*SEQ) + s) * HD;
            #pragma unroll
            for (int ni = 0; ni < 4; ni++) {
                float val = (acc[mi][ni][j] + bias4[ni]) * scale;
                Out[rowbase + hh[ni] * (SEQ*HD) + dd[ni]] = f2b(val);
            }
        }
    }
}

// ---------------- MFMA attention v3 (R8) + exp2-domain softmax ----------------
// Block = (wm, h, half): comb panel staged once in LDS, reused by 16 windows (4 waves x 4 iters).
__global__ __launch_bounds__(256) void attn_mfma(const u16* __restrict__ Qb, const u16* __restrict__ Kb,
                                                 const u16* __restrict__ Vb, const float* __restrict__ comb,
                                                 u16* __restrict__ Ctx) {
    const int tid = threadIdx.x, wv = tid >> 6, lane = tid & 63;
    const int r16 = lane & 15, g = lane >> 4;
    const int bid = blockIdx.x;                   // 0..1535
    const int half = bid & 1, wh = bid >> 1;      // wh = wm*12 + h
    const int wm = wh / NH, h = wh - wm * NH;

    __shared__ float clds[64][68];                // +4 pad: compute reads 2-way-conflict (free)
    {
        const float4* cp = (const float4*)(comb + (size_t)wh * 4096);
        #pragma unroll
        for (int i0 = 0; i0 < 4; i0++) {
            int i = i0 * 256 + tid;               // 1024 float4s, coalesced
            float4 v = cp[i];
            *(float4*)&clds[i >> 4][(i & 15) * 4] = v;
        }
    }
    __syncthreads();

    for (int it = 0; it < 4; it++) {
        const int j = half * 16 + it * 4 + wv;    // 0..31
        const int w = j * 64 + wm;
        const int idx = w * NH + h;
        const u16* Qp = Qb + idx * (SEQ*HD);
        const u16* Kp = Kb + idx * (SEQ*HD);
        const u16* Vp = Vb + idx * (SEQ*HD);
        // NOTE: fragment loads for rows >= 49 read past the panel into the adjacent
        // region — finite deterministic data, masked to p=0 by comb=-1e30.

        bf16x8 kf[4], qf[4];
        #pragma unroll
        for (int ti = 0; ti < 4; ti++) kf[ti] = *(const bf16x8*)&Kp[(ti*16 + r16)*HD + g*8];
        #pragma unroll
        for (int si = 0; si < 4; si++) qf[si] = *(const bf16x8*)&Qp[(si*16 + r16)*HD + g*8];

        f32x4 st[4][4];                           // S^T tiles [ti][si] (exp2-domain)
        __builtin_amdgcn_s_setprio(1);
        #pragma unroll
        for (int ti = 0; ti < 4; ti++)
            #pragma unroll
            for (int si = 0; si < 4; si++) {
                f32x4 z = {0.f,0.f,0.f,0.f};
                st[ti][si] = __builtin_amdgcn_mfma_f32_16x16x32_bf16(kf[ti], qf[si], z, 0, 0, 0);
            }
        __builtin_amdgcn_s_setprio(0);

        // add comb (already x log2e): S^T[t][s] += comb[s][t]
        #pragma unroll
        for (int ti = 0; ti < 4; ti++)
            #pragma unroll
            for (int si = 0; si < 4; si++) {
                const float4 c = *(const float4*)&clds[si*16 + r16][ti*16 + g*4];
                st[ti][si][0] += c.x; st[ti][si][1] += c.y; st[ti][si][2] += c.z; st[ti][si][3] += c.w;
            }

        // softmax over t (per row s): regs (ti,r) + lane bits 4,5; p = 2^(S'-m')
        #pragma unroll
        for (int si = 0; si < 4; si++) {
            float m = st[0][si][0];
            #pragma unroll
            for (int ti = 0; ti < 4; ti++)
                #pragma unroll
                for (int r = 0; r < 4; r++) m = fmaxf(m, st[ti][si][r]);
            m = fmaxf(m, __shfl_xor(m, 16));
            m = fmaxf(m, __shfl_xor(m, 32));
            float sum = 0.f;
            #pragma unroll
            for (int ti = 0; ti < 4; ti++)
                #pragma unroll
                for (int r = 0; r < 4; r++) {
                    float arg = st[ti][si][r] - m;
                    float p;
                    asm("v_exp_f32 %0, %1" : "=v"(p) : "v"(arg));   // 2^arg
                    st[ti][si][r] = p; sum += p;
                }
            sum += __shfl_xor(sum, 16);
            sum += __shfl_xor(sum, 32);
            float rs = 1.0f / sum;
            #pragma unroll
            for (int ti = 0; ti < 4; ti++)
                #pragma unroll
                for (int r = 0; r < 4; r++) st[ti][si][r] *= rs;
        }

        // pack P^T pairs to bf16
        u32 pk[4][4][2];
        #pragma unroll
        for (int ti = 0; ti < 4; ti++)
            #pragma unroll
            for (int si = 0; si < 4; si++)
                #pragma unroll
                for (int q = 0; q < 2; q++) {
                    u32 r;
                    asm("v_cvt_pk_bf16_f32 %0, %1, %2" : "=v"(r) : "v"(st[ti][si][2*q]), "v"(st[ti][si][2*q+1]));
                    pk[ti][si][q] = r;
                }

        // PV A-frags via lane-group shuffles
        bf16x8 pa[2][4];                          // [kc][si]
        const int base_src = r16 + ((g & 1) << 5);
        #pragma unroll
        for (int kc = 0; kc < 2; kc++)
            #pragma unroll
            for (int si = 0; si < 4; si++) {
                union { u32 u[4]; bf16x8 v; } cv;
                #pragma unroll
                for (int jj = 0; jj < 4; jj++) {
                    int srcl = base_src + ((jj >> 1) << 4);
                    u32 x0 = (u32)__shfl((int)pk[kc*2 + 0][si][jj & 1], srcl);
                    u32 x1 = (u32)__shfl((int)pk[kc*2 + 1][si][jj & 1], srcl);
                    cv.u[jj] = (lane >= 32) ? x1 : x0;
                }
                pa[kc][si] = cv.v;
            }

        // V B-frags: B[d][t] = V[t][d]; scalar gather (16-lane groups hit 32B segments, L2-hot)
        bf16x8 vf[2][2];                          // [kc][nt]
        #pragma unroll
        for (int kc = 0; kc < 2; kc++)
            #pragma unroll
            for (int nt = 0; nt < 2; nt++) {
                bf16x8 v;
                #pragma unroll
                for (int i = 0; i < 8; i++)
                    v[i] = (short)Vp[(kc*32 + g*8 + i)*HD + nt*16 + r16];
                vf[kc][nt] = v;
            }

        f32x4 ct[4][2];                           // ctx tiles [si][nt]
        __builtin_amdgcn_s_setprio(1);
        #pragma unroll
        for (int si = 0; si < 4; si++)
            #pragma unroll
            for (int nt = 0; nt < 2; nt++) {
                f32x4 z = {0.f,0.f,0.f,0.f};
                z = __builtin_amdgcn_mfma_f32_16x16x32_bf16(pa[0][si], vf[0][nt], z, 0, 0, 0);
                ct[si][nt] = __builtin_amdgcn_mfma_f32_16x16x32_bf16(pa[1][si], vf[1][nt], z, 0, 0, 0);
            }
        __builtin_amdgcn_s_setprio(0);

        // store ctx[s][d] -> Ctx[w*49+s][h*32+d]
        #pragma unroll
        for (int si = 0; si < 4; si++)
            #pragma unroll
            for (int r = 0; r < 4; r++) {
                int s = si*16 + g*4 + r;
                if (s < SEQ) {
                    #pragma unroll
                    for (int nt = 0; nt < 2; nt++)
                        Ctx[(w*SEQ + s)*DIM + h*HD + nt*16 + r16] = f2b(ct[si][nt][r]);
                }
            }
    }
}

// ---------------- output projection ----------------
__global__ __launch_bounds__(256) void oproj_gemm(const u16* __restrict__ Cb, const u16* __restrict__ Wo,
                                                  const float* __restrict__ ob, float* __restrict__ out) {
    const int bid = blockIdx.x;                   // 0..2351 (= 784*3, %8 == 0)
    const int swz = (bid & 7) * 294 + (bid >> 3);
    const int mTile = swz / 3, nTile = swz - mTile * 3;
    const int mBase = mTile * 128, nBase = nTile * 128;
    f32x4 acc[4][4];
    #pragma unroll
    for (int mi = 0; mi < 4; mi++)
        #pragma unroll
        for (int ni = 0; ni < 4; ni++) { f32x4 z = {0.f,0.f,0.f,0.f}; acc[mi][ni] = z; }

    gemm_tile(Cb + mBase * DIM, Wo + nBase * DIM, acc);

    const int tid = threadIdx.x, wave = tid >> 6, lane = tid & 63;
    const int wm = wave >> 1, wn = wave & 1;
    float ob4[4]; int gn4[4];
    #pragma unroll
    for (int ni = 0; ni < 4; ni++) {
        gn4[ni] = nBase + wn * 64 + ni * 16 + (lane & 15);
        ob4[ni] = ob[gn4[ni]];
    }
    #pragma unroll
    for (int mi = 0; mi < 4; mi++) {
        #pragma unroll
        for (int j = 0; j < 4; j++) {
            int gm = mBase + wm * 64 + mi * 16 + ((lane >> 4) << 2) + j;
            #pragma unroll
            for (int ni = 0; ni < 4; ni++)
                out[gm * DIM + gn4[ni]] = acc[mi][ni][j] + ob4[ni];
        }
    }
}

// ---------------- launch ----------------
extern "C" void kernel_launch(void* const* d_in, const int* in_sizes, int n_in,
                              void* d_out, int out_size, void* d_ws, size_t ws_size,
                              hipStream_t stream) {
    const float* hs   = (const float*)d_in[0];
    const float* mask = (const float*)d_in[1];
    const float* qW   = (const float*)d_in[2];
    const float* qb   = (const float*)d_in[3];
    const float* kW   = (const float*)d_in[4];
    const float* kb   = (const float*)d_in[5];
    const float* vW   = (const float*)d_in[6];
    const float* vb   = (const float*)d_in[7];
    const float* oW   = (const float*)d_in[8];
    const float* ob   = (const float*)d_in[9];
    const float* bt   = (const float*)d_in[10];
    const int*   ridx = (const int*)d_in[11];
    float* out = (float*)d_out;

    char* ws = (char*)d_ws;
    // layout (bytes): Xbf 77,070,336 (aliased by Ctx after QKV) | Q | K | V | Wt | comb(12.6MB)
    u16* Xb   = (u16*)(ws);
    u16* Ctx  = (u16*)(ws);                       // alias: X dead after qkv_gemm
    u16* Qb   = (u16*)(ws + 77070336);
    u16* Kb   = (u16*)(ws + 154140672);
    u16* Vb   = (u16*)(ws + 231211008);
    u16* Wt   = (u16*)(ws + 308281344);
    float* comb = (float*)(ws + 309460992);       // 64*12*64*64 fp32 = 12,582,912 B

    prep_all <<<52224, 256, 0, stream>>>(hs, Xb, qW, kW, vW, oW, Wt, bt, ridx, mask, comb);
    qkv_gemm <<<7056, 256, 0, stream>>>(Xb, Wt, qb, kb, vb, Qb, Kb, Vb);
    attn_mfma<<<1536, 256, 0, stream>>>(Qb, Kb, Vb, comb, Ctx);
    oproj_gemm<<<2352, 256, 0, stream>>>(Ctx, Wt + 3 * WELEM, ob, out);
}